// Round 5
// baseline (1009.406 us; speedup 1.0000x reference)
//
#include <hip/hip_runtime.h>
#include <hip/hip_cooperative_groups.h>
#include <math.h>

namespace cg = cooperative_groups;

#define B 64
#define L 16384
#define C 64
#define D 256
#define H 100
#define F 320
#define EPSV 1e-12f
#define MAXBLK 1024        // cap: 16 chunks per batch
#define RPB 1024           // rows per chunk (L/16)

typedef float nfloat4 __attribute__((ext_vector_type(4)));

__device__ inline float waveReduceSum(float v) {
    v += __shfl_xor(v, 32);
    v += __shfl_xor(v, 16);
    v += __shfl_xor(v, 8);
    v += __shfl_xor(v, 4);
    v += __shfl_xor(v, 2);
    v += __shfl_xor(v, 1);
    return v;
}

// Agent-scope fence + grid barrier: ensures cross-XCD visibility of the
// plain stores (dot2, stats, kv/ev/av) across phases (Guideline 16).
__device__ inline void grid_sync_coherent(cg::grid_group& grid) {
    __threadfence();
    grid.sync();
    __threadfence();
}

// ==================== fused cooperative kernel (grid-stride) ====================
__global__ __launch_bounds__(256, 4) void fused_kernel(
    const float* __restrict__ inputs, const float* __restrict__ reading,
    const float* __restrict__ mem,
    const float* __restrict__ W1, const float* __restrict__ b1,
    const float* __restrict__ W2, const float* __restrict__ b2,
    const float* __restrict__ Wk_r, const float* __restrict__ bk_r,
    const float* __restrict__ Ws_r, const float* __restrict__ bs_r,
    const float* __restrict__ Wk_w, const float* __restrict__ bk_w,
    const float* __restrict__ Ws_w, const float* __restrict__ bs_w,
    const float* __restrict__ We, const float* __restrict__ be,
    const float* __restrict__ Wa, const float* __restrict__ ba,
    float* __restrict__ kv_r, float* __restrict__ kv_w,
    float* __restrict__ ev, float* __restrict__ av,
    float* __restrict__ s_r, float* __restrict__ s_w,
    float* __restrict__ sumsq, float* __restrict__ stats,
    float2* __restrict__ dot2,
    float* __restrict__ out_read, float* __restrict__ new_mem)
{
    cg::grid_group grid = cg::this_grid();
    const int g = blockIdx.x;
    const int nb = gridDim.x;
    const int t = threadIdx.x;
    const int wave = t >> 6, lane = t & 63;
    const int sub = lane >> 4, m = lane & 15;

    __shared__ float feat[F];
    __shared__ float h1[H], h2[H];
    __shared__ float kr_s[C], kw_s[C], ee_s[C], aa_s[C];
    __shared__ float invs[2];
    __shared__ float red0[4], red1[4];
    __shared__ float lds4[4][C];

    // ---------- Phase 0: head MLP (units 0..63); zeroing (units 64..127) ----------
    for (int u = g; u < 2 * B; u += nb) {
        if (u < B) {
            const int b = u;
            feat[t] = inputs[b * D + t];                 // t < 256 == D
            if (t < C) feat[D + t] = reading[b * C + t];
            __syncthreads();
            if (t < H) {
                float acc = b1[t];
                for (int f = 0; f < F; ++f) acc += feat[f] * W1[f * H + t];
                h1[t] = tanhf(acc);
            }
            __syncthreads();
            if (t < H) {
                float acc = b2[t];
                for (int k = 0; k < H; ++k) acc += h1[k] * W2[k * H + t];
                h2[t] = tanhf(acc);
            }
            __syncthreads();
            if (t < C) {
                float a0 = bk_r[t], a1 = bk_w[t], a2 = be[t], a3 = ba[t];
                for (int j = 0; j < H; ++j) {
                    const float hv = h2[j];
                    a0 += hv * Wk_r[j * C + t];
                    a1 += hv * Wk_w[j * C + t];
                    a2 += hv * We[j * C + t];
                    a3 += hv * Wa[j * C + t];
                }
                kr_s[t] = a0; kw_s[t] = a1;
                ee_s[t] = 1.f / (1.f + expf(-a2));
                aa_s[t] = 1.f / (1.f + expf(-a3));
            } else if (t == 64 || t == 65) {
                const float* Ws = (t == 64) ? Ws_r : Ws_w;
                float acc = (t == 64) ? bs_r[0] : bs_w[0];
                for (int j = 0; j < H; ++j) acc += h2[j] * Ws[j];
                const float s = 1.f / (1.f + expf(-acc));
                if (t == 64) s_r[b] = s; else s_w[b] = s;
            }
            __syncthreads();
            if (t < 64) {
                const float xr = kr_s[t], xw = kw_s[t];
                const float nr = waveReduceSum(xr * xr);
                const float nw = waveReduceSum(xw * xw);
                if (t == 0) {
                    invs[0] = 1.f / fmaxf(sqrtf(nr), EPSV);
                    invs[1] = 1.f / fmaxf(sqrtf(nw), EPSV);
                }
            }
            __syncthreads();
            if (t < C) {
                kv_r[b * C + t] = kr_s[t] * invs[0];
                kv_w[b * C + t] = kw_s[t] * invs[1];
                ev[b * C + t] = ee_s[t];
                av[b * C + t] = aa_s[t];
            }
            __syncthreads();
        } else {
            const int b = u - B;
            if (t < C) out_read[b * C + t] = 0.f;
            if (t == 64) sumsq[b] = 0.f;
        }
    }
    grid_sync_coherent(grid);

    // ---------- Phase A: dots + sumsq ----------
    for (int u = g; u < B * 16; u += nb) {
        const int b = u >> 4;
        const int chunk = u & 15;
        const float4 kr = *(const float4*)(kv_r + b * C + m * 4);
        const float4 kw = *(const float4*)(kv_w + b * C + m * 4);
        const float4* memv = (const float4*)(mem + (size_t)b * L * C);
        float2* d2 = dot2 + (size_t)b * L;
        float lss = 0.f;
        const int row0 = chunk * RPB;
        #pragma unroll 4
        for (int it = 0; it < 64; ++it) {
            const int row = row0 + it * 16 + wave * 4 + sub;
            const float4 v = memv[row * 16 + m];
            float pr = v.x * kr.x + v.y * kr.y + v.z * kr.z + v.w * kr.w;
            float pw = v.x * kw.x + v.y * kw.y + v.z * kw.z + v.w * kw.w;
            lss += v.x * v.x + v.y * v.y + v.z * v.z + v.w * v.w;
            pr += __shfl_xor(pr, 1);
            pw += __shfl_xor(pw, 1);
            float x = (m & 1) ? pw : pr;
            x += __shfl_xor(x, 2);
            x += __shfl_xor(x, 4);
            x += __shfl_xor(x, 8);
            const float y = __shfl_xor(x, 1);   // at m==0: y = sum(pw)
            if (m == 0) d2[row] = make_float2(x, y);
        }
        lss = waveReduceSum(lss);
        if (lane == 0) red0[wave] = lss;
        __syncthreads();
        if (t == 0) atomicAdd(&sumsq[b], red0[0] + red0[1] + red0[2] + red0[3]);
        __syncthreads();
    }
    grid_sync_coherent(grid);

    // ---------- Phase S: softmax stats (units 0..63) ----------
    for (int u = g; u < B; u += nb) {
        const int b = u;
        const float invn = 1.f / fmaxf(sqrtf(sumsq[b]), EPSV);
        const float sc_r = s_r[b] * invn;
        const float sc_w = s_w[b] * invn;
        const float2* p = dot2 + (size_t)b * L;

        float mr = -INFINITY, mw = -INFINITY;
        for (int i = t; i < L; i += 256) {
            const float2 d = p[i];
            mr = fmaxf(mr, d.x * sc_r);
            mw = fmaxf(mw, d.y * sc_w);
        }
        #pragma unroll
        for (int off = 32; off; off >>= 1) {
            mr = fmaxf(mr, __shfl_xor(mr, off));
            mw = fmaxf(mw, __shfl_xor(mw, off));
        }
        __syncthreads();
        if (lane == 0) { red0[wave] = mr; red1[wave] = mw; }
        __syncthreads();
        const float bmr = fmaxf(fmaxf(red0[0], red0[1]), fmaxf(red0[2], red0[3]));
        const float bmw = fmaxf(fmaxf(red1[0], red1[1]), fmaxf(red1[2], red1[3]));

        float sr = 0.f, sw = 0.f;
        for (int i = t; i < L; i += 256) {
            const float2 d = p[i];
            sr += expf(d.x * sc_r - bmr);
            sw += expf(d.y * sc_w - bmw);
        }
        sr = waveReduceSum(sr);
        sw = waveReduceSum(sw);
        __syncthreads();
        if (lane == 0) { red0[wave] = sr; red1[wave] = sw; }
        __syncthreads();
        if (t == 0) {
            float* st = stats + b * 8;
            st[0] = sc_r; st[1] = bmr; st[2] = 1.f / (red0[0] + red0[1] + red0[2] + red0[3]);
            st[3] = sc_w; st[4] = bmw; st[5] = 1.f / (red1[0] + red1[1] + red1[2] + red1[3]);
        }
        __syncthreads();
    }
    grid_sync_coherent(grid);

    // ---------- Phase B: new_mem + read-vector ----------
    for (int u = g; u < B * 16; u += nb) {
        const int b = u >> 4;
        const int chunk = u & 15;
        const float4 e4 = *(const float4*)(ev + b * C + m * 4);
        const float4 a4 = *(const float4*)(av + b * C + m * 4);
        const float* st = stats + b * 8;
        const float sc_r = st[0], mx_r = st[1], inv_r = st[2];
        const float sc_w = st[3], mx_w = st[4], inv_w = st[5];
        const float4* memv = (const float4*)(mem + (size_t)b * L * C);
        nfloat4* outv = (nfloat4*)(new_mem + (size_t)b * L * C);
        const float2* d2 = dot2 + (size_t)b * L;

        float4 racc = {0.f, 0.f, 0.f, 0.f};
        const int row0 = chunk * RPB;
        #pragma unroll 2
        for (int it = 0; it < 64; ++it) {
            const int row = row0 + it * 16 + wave * 4 + sub;
            const float2 d = d2[row];
            const float wr = expf(d.x * sc_r - mx_r) * inv_r;
            const float ww = expf(d.y * sc_w - mx_w) * inv_w;
            const float4 v = memv[row * 16 + m];
            nfloat4 nm;
            nm.x = v.x * (1.f - ww * e4.x) + ww * a4.x;
            nm.y = v.y * (1.f - ww * e4.y) + ww * a4.y;
            nm.z = v.z * (1.f - ww * e4.z) + ww * a4.z;
            nm.w = v.w * (1.f - ww * e4.w) + ww * a4.w;
            __builtin_nontemporal_store(nm, &outv[row * 16 + m]);
            racc.x += wr * v.x; racc.y += wr * v.y;
            racc.z += wr * v.z; racc.w += wr * v.w;
        }
        racc.x += __shfl_xor(racc.x, 16); racc.x += __shfl_xor(racc.x, 32);
        racc.y += __shfl_xor(racc.y, 16); racc.y += __shfl_xor(racc.y, 32);
        racc.z += __shfl_xor(racc.z, 16); racc.z += __shfl_xor(racc.z, 32);
        racc.w += __shfl_xor(racc.w, 16); racc.w += __shfl_xor(racc.w, 32);
        __syncthreads();
        if (lane < 16) {
            lds4[wave][m * 4 + 0] = racc.x;
            lds4[wave][m * 4 + 1] = racc.y;
            lds4[wave][m * 4 + 2] = racc.z;
            lds4[wave][m * 4 + 3] = racc.w;
        }
        __syncthreads();
        if (t < 64) {
            const float tot = lds4[0][t] + lds4[1][t] + lds4[2][t] + lds4[3][t];
            atomicAdd(&out_read[b * C + t], tot);
        }
        __syncthreads();
    }
}

// ==================== fallback path: proven 4-kernel pipeline ====================
__global__ __launch_bounds__(128) void head_kernel(
    const float* __restrict__ inputs, const float* __restrict__ reading,
    const float* __restrict__ W1, const float* __restrict__ b1,
    const float* __restrict__ W2, const float* __restrict__ b2,
    const float* __restrict__ Wk_r, const float* __restrict__ bk_r,
    const float* __restrict__ Ws_r, const float* __restrict__ bs_r,
    const float* __restrict__ Wk_w, const float* __restrict__ bk_w,
    const float* __restrict__ Ws_w, const float* __restrict__ bs_w,
    const float* __restrict__ We, const float* __restrict__ be,
    const float* __restrict__ Wa, const float* __restrict__ ba,
    float* __restrict__ kv_r, float* __restrict__ kv_w,
    float* __restrict__ ev, float* __restrict__ av,
    float* __restrict__ s_r, float* __restrict__ s_w)
{
    const int b = blockIdx.x;
    const int t = threadIdx.x;
    __shared__ float feat[F];
    __shared__ float h1[H];
    __shared__ float h2[H];
    __shared__ float kr[C], kw[C], ee[C], aa[C];
    __shared__ float inv_r, inv_w;

    for (int i = t; i < D; i += 128) feat[i] = inputs[b * D + i];
    if (t < C) feat[D + t] = reading[b * C + t];
    __syncthreads();

    if (t < H) {
        float acc = b1[t];
        for (int f = 0; f < F; ++f) acc += feat[f] * W1[f * H + t];
        h1[t] = tanhf(acc);
    }
    __syncthreads();
    if (t < H) {
        float acc = b2[t];
        for (int k = 0; k < H; ++k) acc += h1[k] * W2[k * H + t];
        h2[t] = tanhf(acc);
    }
    __syncthreads();

    if (t < C) {
        float a0 = bk_r[t], a1 = bk_w[t], a2 = be[t], a3 = ba[t];
        for (int j = 0; j < H; ++j) {
            float hv = h2[j];
            a0 += hv * Wk_r[j * C + t];
            a1 += hv * Wk_w[j * C + t];
            a2 += hv * We[j * C + t];
            a3 += hv * Wa[j * C + t];
        }
        kr[t] = a0; kw[t] = a1;
        ee[t] = 1.f / (1.f + expf(-a2));
        aa[t] = 1.f / (1.f + expf(-a3));
    } else if (t == 64 || t == 65) {
        const float* Ws = (t == 64) ? Ws_r : Ws_w;
        float acc = (t == 64) ? bs_r[0] : bs_w[0];
        for (int j = 0; j < H; ++j) acc += h2[j] * Ws[j];
        float s = 1.f / (1.f + expf(-acc));
        if (t == 64) s_r[b] = s; else s_w[b] = s;
    }
    __syncthreads();
    if (t < 64) {
        const float xr = kr[t], xw = kw[t];
        const float nr = waveReduceSum(xr * xr);
        const float nw = waveReduceSum(xw * xw);
        if (t == 0) {
            inv_r = 1.f / fmaxf(sqrtf(nr), EPSV);
            inv_w = 1.f / fmaxf(sqrtf(nw), EPSV);
        }
    }
    __syncthreads();
    if (t < C) {
        kv_r[b * C + t] = kr[t] * inv_r;
        kv_w[b * C + t] = kw[t] * inv_w;
        ev[b * C + t] = ee[t];
        av[b * C + t] = aa[t];
    }
}

__global__ __launch_bounds__(256) void passA_kernel(
    const float* __restrict__ mem,
    const float* __restrict__ kv_r, const float* __restrict__ kv_w,
    float2* __restrict__ dot2,
    float* __restrict__ sumsq)
{
    const int b = blockIdx.y;
    const int t = threadIdx.x;
    const int wave = t >> 6, lane = t & 63;
    const int sub = lane >> 4, m = lane & 15;

    const float4 kr = *(const float4*)(kv_r + b * C + m * 4);
    const float4 kw = *(const float4*)(kv_w + b * C + m * 4);
    const float4* memv = (const float4*)(mem + (size_t)b * L * C);
    float2* d2 = dot2 + (size_t)b * L;

    float lss = 0.f;
    const int row0 = blockIdx.x * 512;
    #pragma unroll 4
    for (int it = 0; it < 32; ++it) {
        const int row = row0 + it * 16 + wave * 4 + sub;
        const float4 v = memv[row * 16 + m];
        float pr = v.x * kr.x + v.y * kr.y + v.z * kr.z + v.w * kr.w;
        float pw = v.x * kw.x + v.y * kw.y + v.z * kw.z + v.w * kw.w;
        lss += v.x * v.x + v.y * v.y + v.z * v.z + v.w * v.w;
        pr += __shfl_xor(pr, 1);
        pw += __shfl_xor(pw, 1);
        float x = (m & 1) ? pw : pr;
        x += __shfl_xor(x, 2);
        x += __shfl_xor(x, 4);
        x += __shfl_xor(x, 8);
        const float y = __shfl_xor(x, 1);
        if (m == 0) d2[row] = make_float2(x, y);
    }
    lss = waveReduceSum(lss);
    __shared__ float wsum[4];
    if (lane == 0) wsum[wave] = lss;
    __syncthreads();
    if (t == 0) atomicAdd(&sumsq[b], wsum[0] + wsum[1] + wsum[2] + wsum[3]);
}

__global__ __launch_bounds__(1024) void stats_kernel(
    const float2* __restrict__ dot2,
    const float* __restrict__ s_r, const float* __restrict__ s_w,
    const float* __restrict__ sumsq,
    float* __restrict__ stats)
{
    const int b = blockIdx.x;
    const int t = threadIdx.x;
    const int wave = t >> 6, lane = t & 63;
    const float invn = 1.f / fmaxf(sqrtf(sumsq[b]), EPSV);
    const float sc_r = s_r[b] * invn;
    const float sc_w = s_w[b] * invn;
    const float2* p = dot2 + (size_t)b * L;

    float2 v[16];
    #pragma unroll
    for (int k = 0; k < 16; ++k) v[k] = p[t + k * 1024];

    float mr = -INFINITY, mw = -INFINITY;
    #pragma unroll
    for (int k = 0; k < 16; ++k) {
        mr = fmaxf(mr, v[k].x * sc_r);
        mw = fmaxf(mw, v[k].y * sc_w);
    }
    #pragma unroll
    for (int off = 32; off; off >>= 1) {
        mr = fmaxf(mr, __shfl_xor(mr, off));
        mw = fmaxf(mw, __shfl_xor(mw, off));
    }
    __shared__ float redr[16], redw[16];
    if (lane == 0) { redr[wave] = mr; redw[wave] = mw; }
    __syncthreads();
    if (t == 0) {
        float a = redr[0], c = redw[0];
        for (int i = 1; i < 16; ++i) { a = fmaxf(a, redr[i]); c = fmaxf(c, redw[i]); }
        redr[0] = a; redw[0] = c;
    }
    __syncthreads();
    const float bmr = redr[0], bmw = redw[0];
    __syncthreads();

    float sr = 0.f, sw = 0.f;
    #pragma unroll
    for (int k = 0; k < 16; ++k) {
        sr += expf(v[k].x * sc_r - bmr);
        sw += expf(v[k].y * sc_w - bmw);
    }
    sr = waveReduceSum(sr);
    sw = waveReduceSum(sw);
    if (lane == 0) { redr[wave] = sr; redw[wave] = sw; }
    __syncthreads();
    if (t == 0) {
        float a = 0.f, c = 0.f;
        for (int i = 0; i < 16; ++i) { a += redr[i]; c += redw[i]; }
        float* st = stats + b * 8;
        st[0] = sc_r; st[1] = bmr; st[2] = 1.f / a;
        st[3] = sc_w; st[4] = bmw; st[5] = 1.f / c;
    }
}

__global__ __launch_bounds__(256) void passB_kernel(
    const float* __restrict__ mem,
    const float2* __restrict__ dot2,
    const float* __restrict__ stats,
    const float* __restrict__ ev, const float* __restrict__ av,
    float* __restrict__ out_read, float* __restrict__ new_mem)
{
    const int b = blockIdx.y;
    const int t = threadIdx.x;
    const int wave = t >> 6, lane = t & 63;
    const int sub = lane >> 4, m = lane & 15;

    const float4 e4 = *(const float4*)(ev + b * C + m * 4);
    const float4 a4 = *(const float4*)(av + b * C + m * 4);
    const float* st = stats + b * 8;
    const float sc_r = st[0], mx_r = st[1], inv_r = st[2];
    const float sc_w = st[3], mx_w = st[4], inv_w = st[5];
    const float4* memv = (const float4*)(mem + (size_t)b * L * C);
    nfloat4* outv = (nfloat4*)(new_mem + (size_t)b * L * C);
    const float2* d2 = dot2 + (size_t)b * L;

    float4 racc = {0.f, 0.f, 0.f, 0.f};
    const int row0 = blockIdx.x * 512;
    #pragma unroll 2
    for (int it = 0; it < 32; ++it) {
        const int row = row0 + it * 16 + wave * 4 + sub;
        const float2 d = d2[row];
        const float wr = expf(d.x * sc_r - mx_r) * inv_r;
        const float ww = expf(d.y * sc_w - mx_w) * inv_w;
        const float4 v = memv[row * 16 + m];
        nfloat4 nm;
        nm.x = v.x * (1.f - ww * e4.x) + ww * a4.x;
        nm.y = v.y * (1.f - ww * e4.y) + ww * a4.y;
        nm.z = v.z * (1.f - ww * e4.z) + ww * a4.z;
        nm.w = v.w * (1.f - ww * e4.w) + ww * a4.w;
        __builtin_nontemporal_store(nm, &outv[row * 16 + m]);
        racc.x += wr * v.x; racc.y += wr * v.y;
        racc.z += wr * v.z; racc.w += wr * v.w;
    }
    racc.x += __shfl_xor(racc.x, 16); racc.x += __shfl_xor(racc.x, 32);
    racc.y += __shfl_xor(racc.y, 16); racc.y += __shfl_xor(racc.y, 32);
    racc.z += __shfl_xor(racc.z, 16); racc.z += __shfl_xor(racc.z, 32);
    racc.w += __shfl_xor(racc.w, 16); racc.w += __shfl_xor(racc.w, 32);
    __shared__ float lds[4][64];
    if (lane < 16) {
        lds[wave][m * 4 + 0] = racc.x;
        lds[wave][m * 4 + 1] = racc.y;
        lds[wave][m * 4 + 2] = racc.z;
        lds[wave][m * 4 + 3] = racc.w;
    }
    __syncthreads();
    if (t < 64) {
        float tot = lds[0][t] + lds[1][t] + lds[2][t] + lds[3][t];
        atomicAdd(&out_read[b * C + t], tot);
    }
}

extern "C" void kernel_launch(void* const* d_in, const int* in_sizes, int n_in,
                              void* d_out, int out_size, void* d_ws, size_t ws_size,
                              hipStream_t stream) {
    const float* inputs  = (const float*)d_in[0];
    const float* reading = (const float*)d_in[1];
    const float* memory  = (const float*)d_in[2];
    const float* W1 = (const float*)d_in[3];
    const float* b1 = (const float*)d_in[4];
    const float* W2 = (const float*)d_in[5];
    const float* b2 = (const float*)d_in[6];
    const float* Wk_r = (const float*)d_in[7];
    const float* bk_r = (const float*)d_in[8];
    const float* Ws_r = (const float*)d_in[9];
    const float* bs_r = (const float*)d_in[10];
    const float* Wk_w = (const float*)d_in[11];
    const float* bk_w = (const float*)d_in[12];
    const float* Ws_w = (const float*)d_in[13];
    const float* bs_w = (const float*)d_in[14];
    const float* We = (const float*)d_in[15];
    const float* be = (const float*)d_in[16];
    const float* Wa = (const float*)d_in[17];
    const float* ba = (const float*)d_in[18];

    float* ws = (float*)d_ws;
    float* kv_r  = ws;                 // B*C
    float* kv_w  = ws + 4096;          // B*C
    float* ev    = ws + 8192;          // B*C
    float* av    = ws + 12288;         // B*C
    float* s_r   = ws + 16384;         // B
    float* s_w   = ws + 16448;         // B
    float* sumsq = ws + 16512;         // B
    float* stats = ws + 16576;         // B*8
    float2* dot2 = (float2*)(ws + 17408);  // B*L*2 floats (16B-aligned)

    float* out = (float*)d_out;
    float* out_read = out;             // B*C
    float* new_mem  = out + 4096;      // B*L*C  (offset 16 KiB: float4-aligned)

    // ---- decide cooperative grid size once (host-side queries; capture-safe) ----
    static int coop_blocks = -2;       // -2 uninit, -1 disabled, >0 grid size
    if (coop_blocks == -2) {
        int dev = 0;
        (void)hipGetDevice(&dev);
        int supports = 0;
        (void)hipDeviceGetAttribute(&supports, hipDeviceAttributeCooperativeLaunch, dev);
        int numCU = 0;
        (void)hipDeviceGetAttribute(&numCU, hipDeviceAttributeMultiprocessorCount, dev);
        int perCU = 0;
        hipError_t oe = hipOccupancyMaxActiveBlocksPerMultiprocessor(
            &perCU, (const void*)fused_kernel, 256, 0);
        if (supports && oe == hipSuccess && perCU > 0 && numCU > 0) {
            long total = (long)perCU * (long)numCU;
            coop_blocks = (int)(total > MAXBLK ? MAXBLK : total);
        } else {
            coop_blocks = -1;
        }
    }

    if (coop_blocks > 0) {
        void* args[] = {
            (void*)&inputs, (void*)&reading, (void*)&memory,
            (void*)&W1, (void*)&b1, (void*)&W2, (void*)&b2,
            (void*)&Wk_r, (void*)&bk_r, (void*)&Ws_r, (void*)&bs_r,
            (void*)&Wk_w, (void*)&bk_w, (void*)&Ws_w, (void*)&bs_w,
            (void*)&We, (void*)&be, (void*)&Wa, (void*)&ba,
            (void*)&kv_r, (void*)&kv_w, (void*)&ev, (void*)&av,
            (void*)&s_r, (void*)&s_w, (void*)&sumsq, (void*)&stats,
            (void*)&dot2, (void*)&out_read, (void*)&new_mem
        };
        hipError_t err = hipLaunchCooperativeKernel(
            (void*)fused_kernel, dim3(coop_blocks), dim3(256), args, 0, stream);
        if (err == hipSuccess) return;
        coop_blocks = -1;   // remember failure; fall through to 4-kernel path
    }

    // ---- fallback: proven 4-kernel pipeline ----
    (void)hipMemsetAsync(sumsq, 0, B * sizeof(float), stream);
    (void)hipMemsetAsync(out_read, 0, B * C * sizeof(float), stream);

    head_kernel<<<B, 128, 0, stream>>>(
        inputs, reading, W1, b1, W2, b2, Wk_r, bk_r, Ws_r, bs_r,
        Wk_w, bk_w, Ws_w, bs_w, We, be, Wa, ba,
        kv_r, kv_w, ev, av, s_r, s_w);

    passA_kernel<<<dim3(32, B), 256, 0, stream>>>(
        memory, kv_r, kv_w, dot2, sumsq);

    stats_kernel<<<B, 1024, 0, stream>>>(
        dot2, s_r, s_w, sumsq, stats);

    passB_kernel<<<dim3(32, B), 256, 0, stream>>>(
        memory, dot2, stats, ev, av, out_read, new_mem);
}

// Round 7
// 580.110 us; speedup vs baseline: 1.7400x; 1.7400x over previous
//
#include <hip/hip_runtime.h>
#include <math.h>

#define B 64
#define L 16384
#define C 64
#define D 256
#define H 100
#define F 320
#define EPSV 1e-12f
#define CHUNKS 32          // chunks per batch
#define RPC 512            // rows per chunk

typedef float nfloat4 __attribute__((ext_vector_type(4)));

__device__ inline float waveReduceSum(float v) {
    v += __shfl_xor(v, 32);
    v += __shfl_xor(v, 16);
    v += __shfl_xor(v, 8);
    v += __shfl_xor(v, 4);
    v += __shfl_xor(v, 2);
    v += __shfl_xor(v, 1);
    return v;
}

// ---------------- K1: sumsq partials (blocks 0..2047) + head MLP (blocks 2048..2111) ----------------
__global__ __launch_bounds__(256) void k1_kernel(
    const float* __restrict__ inputs, const float* __restrict__ reading,
    const float* __restrict__ mem,
    const float* __restrict__ W1, const float* __restrict__ b1,
    const float* __restrict__ W2, const float* __restrict__ b2,
    const float* __restrict__ Wk_r, const float* __restrict__ bk_r,
    const float* __restrict__ Ws_r, const float* __restrict__ bs_r,
    const float* __restrict__ Wk_w, const float* __restrict__ bk_w,
    const float* __restrict__ Ws_w, const float* __restrict__ bs_w,
    const float* __restrict__ We, const float* __restrict__ be,
    const float* __restrict__ Wa, const float* __restrict__ ba,
    float* __restrict__ kv_r, float* __restrict__ kv_w,
    float* __restrict__ ev, float* __restrict__ av,
    float* __restrict__ s_r, float* __restrict__ s_w,
    float* __restrict__ partial_ss)
{
    const int g = blockIdx.x;
    const int t = threadIdx.x;

    if (g < B * CHUNKS) {
        // ---- sumsq over 512 rows ----
        const int b = g >> 5, chunk = g & 31;
        const int wave = t >> 6, lane = t & 63;
        const int sub = lane >> 4, m = lane & 15;
        const float4* memv = (const float4*)(mem + (size_t)b * L * C);
        float lss = 0.f;
        const int row0 = chunk * RPC;
        #pragma unroll 8
        for (int it = 0; it < 32; ++it) {
            const int row = row0 + it * 16 + wave * 4 + sub;
            const float4 v = memv[row * 16 + m];
            lss = fmaf(v.x, v.x, fmaf(v.y, v.y, fmaf(v.z, v.z, fmaf(v.w, v.w, lss))));
        }
        lss = waveReduceSum(lss);
        __shared__ float wsum[4];
        if (lane == 0) wsum[wave] = lss;
        __syncthreads();
        if (t == 0) partial_ss[g] = wsum[0] + wsum[1] + wsum[2] + wsum[3];
    } else {
        // ---- head MLP for batch b (256-thread version, verified in round 5) ----
        const int b = g - B * CHUNKS;
        __shared__ float feat[F];
        __shared__ float h1[H], h2[H];
        __shared__ float kr_s[C], kw_s[C], ee_s[C], aa_s[C];
        __shared__ float invs[2];

        feat[t] = inputs[b * D + t];                 // t < 256 == D
        if (t < C) feat[D + t] = reading[b * C + t];
        __syncthreads();
        if (t < H) {
            float acc = b1[t];
            for (int f = 0; f < F; ++f) acc += feat[f] * W1[f * H + t];
            h1[t] = tanhf(acc);
        }
        __syncthreads();
        if (t < H) {
            float acc = b2[t];
            for (int k = 0; k < H; ++k) acc += h1[k] * W2[k * H + t];
            h2[t] = tanhf(acc);
        }
        __syncthreads();
        if (t < C) {
            float a0 = bk_r[t], a1 = bk_w[t], a2 = be[t], a3 = ba[t];
            for (int j = 0; j < H; ++j) {
                const float hv = h2[j];
                a0 += hv * Wk_r[j * C + t];
                a1 += hv * Wk_w[j * C + t];
                a2 += hv * We[j * C + t];
                a3 += hv * Wa[j * C + t];
            }
            kr_s[t] = a0; kw_s[t] = a1;
            ee_s[t] = 1.f / (1.f + expf(-a2));
            aa_s[t] = 1.f / (1.f + expf(-a3));
        } else if (t == 64 || t == 65) {
            const float* Ws = (t == 64) ? Ws_r : Ws_w;
            float acc = (t == 64) ? bs_r[0] : bs_w[0];
            for (int j = 0; j < H; ++j) acc += h2[j] * Ws[j];
            const float s = 1.f / (1.f + expf(-acc));
            if (t == 64) s_r[b] = s; else s_w[b] = s;
        }
        __syncthreads();
        if (t < 64) {
            const float xr = kr_s[t], xw = kw_s[t];
            const float nr = waveReduceSum(xr * xr);
            const float nw = waveReduceSum(xw * xw);
            if (t == 0) {
                invs[0] = 1.f / fmaxf(sqrtf(nr), EPSV);
                invs[1] = 1.f / fmaxf(sqrtf(nw), EPSV);
            }
        }
        __syncthreads();
        if (t < C) {
            kv_r[b * C + t] = kr_s[t] * invs[0];
            kv_w[b * C + t] = kw_s[t] * invs[1];
            ev[b * C + t] = ee_s[t];
            av[b * C + t] = aa_s[t];
        }
    }
}

// ---------------- K2: exp-sums (dots recomputed; mem is L3-resident) ----------------
// No max-subtraction: dot*sc <= row_norm/||mem||_F <= 1 for ANY input
// (Cauchy-Schwarz, kvec unit norm, s in (0,1)), so exp is bounded by e
// and the softmax ratio is mathematically identical.
__global__ __launch_bounds__(256) void k2_kernel(
    const float* __restrict__ mem,
    const float* __restrict__ kv_r, const float* __restrict__ kv_w,
    const float* __restrict__ s_r, const float* __restrict__ s_w,
    const float* __restrict__ partial_ss,
    float* __restrict__ partial_S, float* __restrict__ out_read)
{
    const int b = blockIdx.y;
    const int chunk = blockIdx.x;
    const int t = threadIdx.x;
    const int wave = t >> 6, lane = t & 63;
    const int sub = lane >> 4, m = lane & 15;

    // zero out_read for K3's atomics (kernel boundary orders this before K3)
    if (chunk == 0 && t < C) out_read[b * C + t] = 0.f;

    // reduce sumsq partials -> scales
    __shared__ float sc_sh[2];
    if (t < 64) {
        float p = (t < CHUNKS) ? partial_ss[b * CHUNKS + t] : 0.f;
        p = waveReduceSum(p);
        if (t == 0) {
            const float invn = 1.f / fmaxf(sqrtf(p), EPSV);
            sc_sh[0] = s_r[b] * invn;
            sc_sh[1] = s_w[b] * invn;
        }
    }
    __syncthreads();
    const float sc_r = sc_sh[0], sc_w = sc_sh[1];

    const float4 kr = *(const float4*)(kv_r + b * C + m * 4);
    const float4 kw = *(const float4*)(kv_w + b * C + m * 4);
    const float4* memv = (const float4*)(mem + (size_t)b * L * C);

    float er = 0.f, ew = 0.f;
    const int row0 = chunk * RPC;
    #pragma unroll 4
    for (int it = 0; it < 32; ++it) {
        const int row = row0 + it * 16 + wave * 4 + sub;
        const float4 v = memv[row * 16 + m];
        float pr = v.x * kr.x + v.y * kr.y + v.z * kr.z + v.w * kr.w;
        float pw = v.x * kw.x + v.y * kw.y + v.z * kw.z + v.w * kw.w;
        pr += __shfl_xor(pr, 1);
        pw += __shfl_xor(pw, 1);
        float x = (m & 1) ? pw : pr;
        x += __shfl_xor(x, 2);
        x += __shfl_xor(x, 4);
        x += __shfl_xor(x, 8);
        const float y = __shfl_xor(x, 1);
        if (m == 0) {                      // even lane: x = dot_r, y = dot_w
            er += expf(x * sc_r);
            ew += expf(y * sc_w);
        }
    }
    er = waveReduceSum(er);                // non-m==0 lanes contribute 0
    ew = waveReduceSum(ew);
    __shared__ float wr_sh[4], ww_sh[4];
    if (lane == 0) { wr_sh[wave] = er; ww_sh[wave] = ew; }
    __syncthreads();
    if (t == 0) {
        float* ps = partial_S + (size_t)(b * CHUNKS + chunk) * 2;
        ps[0] = wr_sh[0] + wr_sh[1] + wr_sh[2] + wr_sh[3];
        ps[1] = ww_sh[0] + ww_sh[1] + ww_sh[2] + ww_sh[3];
    }
}

// ---------------- K3: recompute dots, apply softmax weights, write new_mem + read-vec ----------------
__global__ __launch_bounds__(256) void k3_kernel(
    const float* __restrict__ mem,
    const float* __restrict__ kv_r, const float* __restrict__ kv_w,
    const float* __restrict__ s_r, const float* __restrict__ s_w,
    const float* __restrict__ partial_ss, const float* __restrict__ partial_S,
    const float* __restrict__ ev, const float* __restrict__ av,
    float* __restrict__ out_read, float* __restrict__ new_mem)
{
    const int b = blockIdx.y;
    const int chunk = blockIdx.x;
    const int t = threadIdx.x;
    const int wave = t >> 6, lane = t & 63;
    const int sub = lane >> 4, m = lane & 15;

    // reduce partials: wave0 -> sumsq, wave1 -> S_r, wave2 -> S_w
    __shared__ float tmp_sh[3];
    __shared__ float st_sh[4];
    if (wave == 0) {
        float p = (lane < CHUNKS) ? partial_ss[b * CHUNKS + lane] : 0.f;
        p = waveReduceSum(p);
        if (lane == 0) tmp_sh[0] = p;
    } else if (wave == 1) {
        float p = (lane < CHUNKS) ? partial_S[(size_t)(b * CHUNKS + lane) * 2] : 0.f;
        p = waveReduceSum(p);
        if (lane == 0) tmp_sh[1] = p;
    } else if (wave == 2) {
        float p = (lane < CHUNKS) ? partial_S[(size_t)(b * CHUNKS + lane) * 2 + 1] : 0.f;
        p = waveReduceSum(p);
        if (lane == 0) tmp_sh[2] = p;
    }
    __syncthreads();
    if (t == 0) {
        const float invn = 1.f / fmaxf(sqrtf(tmp_sh[0]), EPSV);
        st_sh[0] = s_r[b] * invn;        // sc_r
        st_sh[1] = s_w[b] * invn;        // sc_w
        st_sh[2] = 1.f / tmp_sh[1];      // inv_r
        st_sh[3] = 1.f / tmp_sh[2];      // inv_w
    }
    __syncthreads();
    const float sc_r = st_sh[0], sc_w = st_sh[1];
    const float inv_r = st_sh[2], inv_w = st_sh[3];

    const float4 kr = *(const float4*)(kv_r + b * C + m * 4);
    const float4 kw = *(const float4*)(kv_w + b * C + m * 4);
    const float4 e4 = *(const float4*)(ev + b * C + m * 4);
    const float4 a4 = *(const float4*)(av + b * C + m * 4);
    const float4* memv = (const float4*)(mem + (size_t)b * L * C);
    nfloat4* outv = (nfloat4*)(new_mem + (size_t)b * L * C);

    float4 racc = {0.f, 0.f, 0.f, 0.f};
    const int row0 = chunk * RPC;
    #pragma unroll 4
    for (int it = 0; it < 32; ++it) {
        const int row = row0 + it * 16 + wave * 4 + sub;
        const float4 v = memv[row * 16 + m];
        float pr = v.x * kr.x + v.y * kr.y + v.z * kr.z + v.w * kr.w;
        float pw = v.x * kw.x + v.y * kw.y + v.z * kw.z + v.w * kw.w;
        pr += __shfl_xor(pr, 1);
        pw += __shfl_xor(pw, 1);
        float x = (m & 1) ? pw : pr;
        x += __shfl_xor(x, 2);
        x += __shfl_xor(x, 4);
        x += __shfl_xor(x, 8);
        const float y = __shfl_xor(x, 1);
        // parity trick: after the xor tree, even lanes hold full dot_r in x
        // and dot_w in y; odd lanes the reverse. All 16 lanes get both.
        const float dr = (m & 1) ? y : x;
        const float dw = (m & 1) ? x : y;
        const float wr = expf(dr * sc_r) * inv_r;
        const float ww = expf(dw * sc_w) * inv_w;
        nfloat4 nm;
        nm.x = v.x * (1.f - ww * e4.x) + ww * a4.x;
        nm.y = v.y * (1.f - ww * e4.y) + ww * a4.y;
        nm.z = v.z * (1.f - ww * e4.z) + ww * a4.z;
        nm.w = v.w * (1.f - ww * e4.w) + ww * a4.w;
        __builtin_nontemporal_store(nm, &outv[row * 16 + m]);
        racc.x = fmaf(wr, v.x, racc.x);
        racc.y = fmaf(wr, v.y, racc.y);
        racc.z = fmaf(wr, v.z, racc.z);
        racc.w = fmaf(wr, v.w, racc.w);
    }
    // fold lanes sharing the same column-quad m (xor 16, 32)
    racc.x += __shfl_xor(racc.x, 16); racc.x += __shfl_xor(racc.x, 32);
    racc.y += __shfl_xor(racc.y, 16); racc.y += __shfl_xor(racc.y, 32);
    racc.z += __shfl_xor(racc.z, 16); racc.z += __shfl_xor(racc.z, 32);
    racc.w += __shfl_xor(racc.w, 16); racc.w += __shfl_xor(racc.w, 32);
    __shared__ float lds[4][64];
    if (lane < 16) {
        lds[wave][m * 4 + 0] = racc.x;
        lds[wave][m * 4 + 1] = racc.y;
        lds[wave][m * 4 + 2] = racc.z;
        lds[wave][m * 4 + 3] = racc.w;
    }
    __syncthreads();
    if (t < 64) {
        const float tot = lds[0][t] + lds[1][t] + lds[2][t] + lds[3][t];
        atomicAdd(&out_read[b * C + t], tot);
    }
}

extern "C" void kernel_launch(void* const* d_in, const int* in_sizes, int n_in,
                              void* d_out, int out_size, void* d_ws, size_t ws_size,
                              hipStream_t stream) {
    const float* inputs  = (const float*)d_in[0];
    const float* reading = (const float*)d_in[1];
    const float* memory  = (const float*)d_in[2];
    const float* W1 = (const float*)d_in[3];
    const float* b1 = (const float*)d_in[4];
    const float* W2 = (const float*)d_in[5];
    const float* b2 = (const float*)d_in[6];
    const float* Wk_r = (const float*)d_in[7];
    const float* bk_r = (const float*)d_in[8];
    const float* Ws_r = (const float*)d_in[9];
    const float* bs_r = (const float*)d_in[10];
    const float* Wk_w = (const float*)d_in[11];
    const float* bk_w = (const float*)d_in[12];
    const float* Ws_w = (const float*)d_in[13];
    const float* bs_w = (const float*)d_in[14];
    const float* We = (const float*)d_in[15];
    const float* be = (const float*)d_in[16];
    const float* Wa = (const float*)d_in[17];
    const float* ba = (const float*)d_in[18];

    float* ws = (float*)d_ws;
    float* kv_r       = ws;            // B*C
    float* kv_w       = ws + 4096;     // B*C
    float* ev         = ws + 8192;     // B*C
    float* av         = ws + 12288;    // B*C
    float* s_r        = ws + 16384;    // B
    float* s_w        = ws + 16448;    // B
    float* partial_ss = ws + 16512;    // B*32
    float* partial_S  = ws + 18560;    // B*32*2

    float* out = (float*)d_out;
    float* out_read = out;             // B*C
    float* new_mem  = out + 4096;      // B*L*C  (offset 16 KiB: float4-aligned)

    k1_kernel<<<B * CHUNKS + B, 256, 0, stream>>>(
        inputs, reading, memory, W1, b1, W2, b2,
        Wk_r, bk_r, Ws_r, bs_r, Wk_w, bk_w, Ws_w, bs_w,
        We, be, Wa, ba,
        kv_r, kv_w, ev, av, s_r, s_w, partial_ss);

    k2_kernel<<<dim3(CHUNKS, B), 256, 0, stream>>>(
        memory, kv_r, kv_w, s_r, s_w, partial_ss, partial_S, out_read);

    k3_kernel<<<dim3(CHUNKS, B), 256, 0, stream>>>(
        memory, kv_r, kv_w, s_r, s_w, partial_ss, partial_S,
        ev, av, out_read, new_mem);
}

// Round 8
// 565.235 us; speedup vs baseline: 1.7858x; 1.0263x over previous
//
#include <hip/hip_runtime.h>
#include <math.h>

#define B 64
#define L 16384
#define C 64
#define D 256
#define H 100
#define F 320
#define EPSV 1e-12f
#define CHUNKS 32          // chunks per batch
#define RPC 512            // rows per chunk

typedef float nfloat4 __attribute__((ext_vector_type(4)));

__device__ inline float waveReduceSum(float v) {
    v += __shfl_xor(v, 32);
    v += __shfl_xor(v, 16);
    v += __shfl_xor(v, 8);
    v += __shfl_xor(v, 4);
    v += __shfl_xor(v, 2);
    v += __shfl_xor(v, 1);
    return v;
}

// ---------------- K1: redundant head MLP + sumsq partials + dots (one HBM pass) ----------------
// Every block recomputes the head MLP for its batch (bitwise deterministic:
// same inputs, same instruction sequence) -> no cross-block dependency, no
// extra kernel boundary. Cost ~2-4 us/block, fully overlapped; W1/W2 served
// from L2 across the 32 blocks sharing each batch.
__global__ __launch_bounds__(256) void k1_kernel(
    const float* __restrict__ inputs, const float* __restrict__ reading,
    const float* __restrict__ mem,
    const float* __restrict__ W1, const float* __restrict__ b1,
    const float* __restrict__ W2, const float* __restrict__ b2,
    const float* __restrict__ Wk_r, const float* __restrict__ bk_r,
    const float* __restrict__ Ws_r, const float* __restrict__ bs_r,
    const float* __restrict__ Wk_w, const float* __restrict__ bk_w,
    const float* __restrict__ Ws_w, const float* __restrict__ bs_w,
    const float* __restrict__ We, const float* __restrict__ be,
    const float* __restrict__ Wa, const float* __restrict__ ba,
    float* __restrict__ ev, float* __restrict__ av,
    float* __restrict__ s_r, float* __restrict__ s_w,
    float* __restrict__ partial_ss, float2* __restrict__ dot2)
{
    const int g = blockIdx.x;
    const int b = g >> 5, chunk = g & 31;
    const int t = threadIdx.x;
    const int wave = t >> 6, lane = t & 63;
    const int sub = lane >> 4, m = lane & 15;

    __shared__ float feat[F];
    __shared__ float h1[H], h2[H];
    __shared__ float kr_s[C], kw_s[C];
    __shared__ float invs[2];

    // ---- head MLP (redundant per block) ----
    feat[t] = inputs[b * D + t];                 // t < 256 == D
    if (t < C) feat[D + t] = reading[b * C + t];
    __syncthreads();
    if (t < H) {
        float acc = b1[t];
        for (int f = 0; f < F; ++f) acc += feat[f] * W1[f * H + t];
        h1[t] = tanhf(acc);
    }
    __syncthreads();
    if (t < H) {
        float acc = b2[t];
        for (int k = 0; k < H; ++k) acc += h1[k] * W2[k * H + t];
        h2[t] = tanhf(acc);
    }
    __syncthreads();
    if (t < C) {
        float a0 = bk_r[t], a1 = bk_w[t], a2 = be[t], a3 = ba[t];
        for (int j = 0; j < H; ++j) {
            const float hv = h2[j];
            a0 += hv * Wk_r[j * C + t];
            a1 += hv * Wk_w[j * C + t];
            a2 += hv * We[j * C + t];
            a3 += hv * Wa[j * C + t];
        }
        kr_s[t] = a0; kw_s[t] = a1;
        if (chunk == 0) {
            ev[b * C + t] = 1.f / (1.f + expf(-a2));
            av[b * C + t] = 1.f / (1.f + expf(-a3));
        }
    } else if (t == 64 || t == 65) {
        const float* Ws = (t == 64) ? Ws_r : Ws_w;
        float acc = (t == 64) ? bs_r[0] : bs_w[0];
        for (int j = 0; j < H; ++j) acc += h2[j] * Ws[j];
        const float s = 1.f / (1.f + expf(-acc));
        if (chunk == 0) { if (t == 64) s_r[b] = s; else s_w[b] = s; }
    }
    __syncthreads();
    if (t < 64) {
        const float xr = kr_s[t], xw = kw_s[t];
        const float nr = waveReduceSum(xr * xr);
        const float nw = waveReduceSum(xw * xw);
        if (t == 0) {
            invs[0] = 1.f / fmaxf(sqrtf(nr), EPSV);
            invs[1] = 1.f / fmaxf(sqrtf(nw), EPSV);
        }
    }
    __syncthreads();
    if (t < 64) {
        kr_s[t] *= invs[0];
        kw_s[t] *= invs[1];
    }
    __syncthreads();

    // ---- stream this chunk: sumsq + dots -> dot2 ----
    const float4 kr = *(const float4*)(kr_s + m * 4);
    const float4 kw = *(const float4*)(kw_s + m * 4);
    const float4* memv = (const float4*)(mem + (size_t)b * L * C);
    float2* d2 = dot2 + (size_t)b * L;

    float lss = 0.f;
    const int row0 = chunk * RPC;
    #pragma unroll 4
    for (int it = 0; it < 32; ++it) {
        const int row = row0 + it * 16 + wave * 4 + sub;
        const float4 v = memv[row * 16 + m];
        float pr = v.x * kr.x + v.y * kr.y + v.z * kr.z + v.w * kr.w;
        float pw = v.x * kw.x + v.y * kw.y + v.z * kw.z + v.w * kw.w;
        lss = fmaf(v.x, v.x, fmaf(v.y, v.y, fmaf(v.z, v.z, fmaf(v.w, v.w, lss))));
        pr += __shfl_xor(pr, 1);
        pw += __shfl_xor(pw, 1);
        float x = (m & 1) ? pw : pr;
        x += __shfl_xor(x, 2);
        x += __shfl_xor(x, 4);
        x += __shfl_xor(x, 8);
        const float y = __shfl_xor(x, 1);   // at m==0: x = dot_r, y = dot_w
        if (m == 0) d2[row] = make_float2(x, y);
    }
    lss = waveReduceSum(lss);
    __shared__ float wsum[4];
    if (lane == 0) wsum[wave] = lss;
    __syncthreads();
    if (t == 0) partial_ss[g] = wsum[0] + wsum[1] + wsum[2] + wsum[3];
}

// ---------------- K2: softmax stats from dot2 (16 MB, L2/L3-hot) ----------------
// No max-subtraction: dot*sc <= row_norm/||M||_F <= 1 for ANY input
// (Cauchy-Schwarz, kvec unit norm, s in (0,1)), so exp <= e.
__global__ __launch_bounds__(1024) void k2_kernel(
    const float2* __restrict__ dot2,
    const float* __restrict__ s_r, const float* __restrict__ s_w,
    const float* __restrict__ partial_ss,
    float* __restrict__ stats, float* __restrict__ out_read)
{
    const int b = blockIdx.x;
    const int t = threadIdx.x;
    const int wave = t >> 6, lane = t & 63;

    if (t < C) out_read[b * C + t] = 0.f;

    __shared__ float sc_sh[2];
    if (t < 64) {
        float p = (t < CHUNKS) ? partial_ss[b * CHUNKS + t] : 0.f;
        p = waveReduceSum(p);
        if (t == 0) {
            const float invn = 1.f / fmaxf(sqrtf(p), EPSV);
            sc_sh[0] = s_r[b] * invn;
            sc_sh[1] = s_w[b] * invn;
        }
    }
    __syncthreads();
    const float sc_r = sc_sh[0], sc_w = sc_sh[1];

    const float2* p = dot2 + (size_t)b * L;
    float er = 0.f, ew = 0.f;
    #pragma unroll
    for (int k = 0; k < 16; ++k) {
        const float2 d = p[t + k * 1024];
        er += expf(d.x * sc_r);
        ew += expf(d.y * sc_w);
    }
    er = waveReduceSum(er);
    ew = waveReduceSum(ew);
    __shared__ float redr[16], redw[16];
    if (lane == 0) { redr[wave] = er; redw[wave] = ew; }
    __syncthreads();
    if (t == 0) {
        float a = 0.f, c = 0.f;
        for (int i = 0; i < 16; ++i) { a += redr[i]; c += redw[i]; }
        float* st = stats + b * 8;
        st[0] = sc_r; st[1] = 1.f / a;
        st[2] = sc_w; st[3] = 1.f / c;
    }
}

// ---------------- K3: weights from dot2, write new_mem + read-vector (one L3 read + HBM write pass) ----------------
__global__ __launch_bounds__(256) void k3_kernel(
    const float* __restrict__ mem,
    const float2* __restrict__ dot2,
    const float* __restrict__ stats,
    const float* __restrict__ ev, const float* __restrict__ av,
    float* __restrict__ out_read, float* __restrict__ new_mem)
{
    const int b = blockIdx.y;
    const int chunk = blockIdx.x;
    const int t = threadIdx.x;
    const int wave = t >> 6, lane = t & 63;
    const int sub = lane >> 4, m = lane & 15;

    const float4 st4 = *(const float4*)(stats + b * 8);
    const float sc_r = st4.x, inv_r = st4.y, sc_w = st4.z, inv_w = st4.w;
    const float4 e4 = *(const float4*)(ev + b * C + m * 4);
    const float4 a4 = *(const float4*)(av + b * C + m * 4);
    const float4* memv = (const float4*)(mem + (size_t)b * L * C);
    nfloat4* outv = (nfloat4*)(new_mem + (size_t)b * L * C);
    const float2* d2 = dot2 + (size_t)b * L;

    float4 racc = {0.f, 0.f, 0.f, 0.f};
    const int row0 = chunk * RPC;
    #pragma unroll 4
    for (int it = 0; it < 32; ++it) {
        const int row = row0 + it * 16 + wave * 4 + sub;
        const float2 d = d2[row];              // uniform across the 16-lane group
        const float wr = expf(d.x * sc_r) * inv_r;
        const float ww = expf(d.y * sc_w) * inv_w;
        const float4 v = memv[row * 16 + m];
        nfloat4 nm;
        nm.x = v.x * (1.f - ww * e4.x) + ww * a4.x;
        nm.y = v.y * (1.f - ww * e4.y) + ww * a4.y;
        nm.z = v.z * (1.f - ww * e4.z) + ww * a4.z;
        nm.w = v.w * (1.f - ww * e4.w) + ww * a4.w;
        __builtin_nontemporal_store(nm, &outv[row * 16 + m]);
        racc.x = fmaf(wr, v.x, racc.x);
        racc.y = fmaf(wr, v.y, racc.y);
        racc.z = fmaf(wr, v.z, racc.z);
        racc.w = fmaf(wr, v.w, racc.w);
    }
    // fold lanes sharing the same column-quad m (xor 16, 32)
    racc.x += __shfl_xor(racc.x, 16); racc.x += __shfl_xor(racc.x, 32);
    racc.y += __shfl_xor(racc.y, 16); racc.y += __shfl_xor(racc.y, 32);
    racc.z += __shfl_xor(racc.z, 16); racc.z += __shfl_xor(racc.z, 32);
    racc.w += __shfl_xor(racc.w, 16); racc.w += __shfl_xor(racc.w, 32);
    __shared__ float lds[4][64];
    if (lane < 16) {
        lds[wave][m * 4 + 0] = racc.x;
        lds[wave][m * 4 + 1] = racc.y;
        lds[wave][m * 4 + 2] = racc.z;
        lds[wave][m * 4 + 3] = racc.w;
    }
    __syncthreads();
    if (t < 64) {
        const float tot = lds[0][t] + lds[1][t] + lds[2][t] + lds[3][t];
        atomicAdd(&out_read[b * C + t], tot);
    }
}

extern "C" void kernel_launch(void* const* d_in, const int* in_sizes, int n_in,
                              void* d_out, int out_size, void* d_ws, size_t ws_size,
                              hipStream_t stream) {
    const float* inputs  = (const float*)d_in[0];
    const float* reading = (const float*)d_in[1];
    const float* memory  = (const float*)d_in[2];
    const float* W1 = (const float*)d_in[3];
    const float* b1 = (const float*)d_in[4];
    const float* W2 = (const float*)d_in[5];
    const float* b2 = (const float*)d_in[6];
    const float* Wk_r = (const float*)d_in[7];
    const float* bk_r = (const float*)d_in[8];
    const float* Ws_r = (const float*)d_in[9];
    const float* bs_r = (const float*)d_in[10];
    const float* Wk_w = (const float*)d_in[11];
    const float* bk_w = (const float*)d_in[12];
    const float* Ws_w = (const float*)d_in[13];
    const float* bs_w = (const float*)d_in[14];
    const float* We = (const float*)d_in[15];
    const float* be = (const float*)d_in[16];
    const float* Wa = (const float*)d_in[17];
    const float* ba = (const float*)d_in[18];

    float* ws = (float*)d_ws;
    float* ev         = ws;            // B*C
    float* av         = ws + 4096;     // B*C
    float* s_r        = ws + 8192;     // B
    float* s_w        = ws + 8256;     // B
    float* partial_ss = ws + 8320;     // B*32
    float* stats      = ws + 10368;    // B*8
    float2* dot2      = (float2*)(ws + 11264);  // B*L*2 floats (16B-aligned)

    float* out = (float*)d_out;
    float* out_read = out;             // B*C
    float* new_mem  = out + 4096;      // B*L*C  (offset 16 KiB: float4-aligned)

    k1_kernel<<<B * CHUNKS, 256, 0, stream>>>(
        inputs, reading, memory, W1, b1, W2, b2,
        Wk_r, bk_r, Ws_r, bs_r, Wk_w, bk_w, Ws_w, bs_w,
        We, be, Wa, ba,
        ev, av, s_r, s_w, partial_ss, dot2);

    k2_kernel<<<B, 1024, 0, stream>>>(
        dot2, s_r, s_w, partial_ss, stats, out_read);

    k3_kernel<<<dim3(CHUNKS, B), 256, 0, stream>>>(
        memory, dot2, stats, ev, av, out_read, new_mem);
}